// Round 2
// baseline (2455.883 us; speedup 1.0000x reference)
//
#include <hip/hip_runtime.h>
#include <hip/hip_bf16.h>

typedef unsigned short u16;
typedef __bf16 b16;
typedef u16 u16x8 __attribute__((ext_vector_type(8)));
typedef b16 b16x8 __attribute__((ext_vector_type(8)));
typedef float f32x4 __attribute__((ext_vector_type(4)));

#define NN 50000
#define NE 800000
#define D  300
#define DP 320   // padded feature dim
#define HP 640   // padded hidden dim

__device__ __forceinline__ float b2f(u16 u){ unsigned v = ((unsigned)u) << 16; float f; __builtin_memcpy(&f, &v, 4); return f; }
__device__ __forceinline__ u16 f2b(float f){ __hip_bfloat16 h = __float2bfloat16(f); u16 u; __builtin_memcpy(&u, &h, 2); return u; }

__device__ __forceinline__ void gl_lds16(const void* g, void* l){
  __builtin_amdgcn_global_load_lds((const __attribute__((address_space(1))) unsigned int*)g,
                                   (__attribute__((address_space(3))) unsigned int*)l, 16, 0, 0);
}

__device__ __forceinline__ f32x4 mfma_bf16(u16x8 a, u16x8 b, f32x4 c){
  return __builtin_amdgcn_mfma_f32_16x16x32_bf16(__builtin_bit_cast(b16x8, a),
                                                 __builtin_bit_cast(b16x8, b), c, 0, 0, 0);
}

// ---------------- CSR build (by dst) ----------------
__global__ void k_count(const int* __restrict__ ei, int* __restrict__ cnt){
  int e = blockIdx.x * 256 + threadIdx.x;
  if (e < NE) atomicAdd(&cnt[ei[NE + e]], 1);
}

__global__ void k_scan1(const int* __restrict__ cnt, int* __restrict__ rp, int* __restrict__ bsum){
  __shared__ int s[1024];
  int i = blockIdx.x * 1024 + threadIdx.x;
  int v = (i < NN) ? cnt[i] : 0;
  s[threadIdx.x] = v;
  __syncthreads();
  for (int off = 1; off < 1024; off <<= 1){
    int t = (threadIdx.x >= off) ? s[threadIdx.x - off] : 0;
    __syncthreads();
    s[threadIdx.x] += t;
    __syncthreads();
  }
  if (i < NN) rp[i] = s[threadIdx.x] - v;
  if (threadIdx.x == 1023) bsum[blockIdx.x] = s[1023];
}

__global__ void k_scan2(int* __restrict__ bsum, int nb){
  __shared__ int s[64];
  int v = (threadIdx.x < nb) ? bsum[threadIdx.x] : 0;
  s[threadIdx.x] = v; __syncthreads();
  for (int off = 1; off < 64; off <<= 1){
    int t = (threadIdx.x >= off) ? s[threadIdx.x - off] : 0;
    __syncthreads();
    s[threadIdx.x] += t;
    __syncthreads();
  }
  if (threadIdx.x < nb) bsum[threadIdx.x] = s[threadIdx.x] - v;
}

__global__ void k_scan3(int* __restrict__ rp, int* __restrict__ cur, const int* __restrict__ bsum){
  int i = blockIdx.x * 256 + threadIdx.x;
  if (i < NN){ int v = rp[i] + bsum[i >> 10]; rp[i] = v; cur[i] = v; }
  if (i == 0) rp[NN] = NE;
}

__global__ void k_fill(const int* __restrict__ ei, const int* __restrict__ ea,
                       int* __restrict__ cur, int* __restrict__ pack){
  int e = blockIdx.x * 256 + threadIdx.x;
  if (e >= NE) return;
  int d = ei[NE + e];
  int pos = atomicAdd(&cur[d], 1);
  pack[pos] = ei[e] | (((ea[2*e] << 3) | ea[2*e + 1]) << 16);
}

// ---------------- weight transpose + pad -> split bf16 ----------------
// W1t: [5][HP][DP]  (n-major, contiguous K) ; W2t: [5][DP][HP]
__global__ void k_wconv(const float* __restrict__ W1, const float* __restrict__ W2,
                        u16* __restrict__ W1h, u16* __restrict__ W1l,
                        u16* __restrict__ W2h, u16* __restrict__ W2l){
  int i = blockIdx.x * 256 + threadIdx.x;
  {
    int l = i / (HP * DP); int rem = i % (HP * DP); int n = rem / DP, k = rem % DP;
    float v = (n < 600 && k < D) ? W1[((size_t)l * D + k) * 600 + n] : 0.f;
    u16 h = f2b(v);
    W1h[i] = h; W1l[i] = f2b(v - b2f(h));
  }
  {
    int l = i / (DP * HP); int rem = i % (DP * HP); int n = rem / HP, k = rem % HP;
    float v = (n < D && k < 600) ? W2[((size_t)l * 600 + k) * D + n] : 0.f;
    u16 h = f2b(v);
    W2h[i] = h; W2l[i] = f2b(v - b2f(h));
  }
}

// ---------------- node embedding -> fp32 padded ----------------
__global__ void k_nodeemb(const int* __restrict__ x, const float* __restrict__ xemb, float* __restrict__ hbf){
  int v = blockIdx.x, c = threadIdx.x;  // block = DP threads
  float y = 0.f;
  if (c < D){
    int a = x[2*v], b = x[2*v + 1];
    y = xemb[(size_t)a * D + c] + xemb[(size_t)b * D + c];
  }
  hbf[(size_t)v * DP + c] = y;
}

// ---------------- per-layer aggregation: one wave per node, fp32 in, split-bf16 out ----------------
__global__ __launch_bounds__(256) void k_agg(const float* __restrict__ hbf, const int* __restrict__ rp,
    const int* __restrict__ pack, const float* __restrict__ eemb,
    u16* __restrict__ aggh, u16* __restrict__ aggl){
  __shared__ float semb[6 * DP];
  for (int i = threadIdx.x; i < 6 * DP; i += 256){
    int r = i / DP, c = i % DP;
    semb[i] = (c < D) ? eemb[r * D + c] : 0.f;
  }
  __syncthreads();
  int wid = threadIdx.x >> 6, lane = threadIdx.x & 63;
  int v = blockIdx.x * 4 + wid;
  if (v >= NN) return;
  float acc[5];
  #pragma unroll
  for (int j = 0; j < 5; ++j){                 // self-loop: attr (4,0)
    int c = lane + 64 * j;
    acc[j] = hbf[(size_t)v * DP + c] + semb[4 * DP + c] + semb[0 * DP + c];
  }
  int p1 = rp[v + 1];
  for (int p = rp[v]; p < p1; ++p){
    int pk = pack[p];
    int s = pk & 0xFFFF;
    const float* e0 = &semb[((pk >> 19) & 7) * DP];
    const float* e1 = &semb[((pk >> 16) & 7) * DP];
    const float* hr = &hbf[(size_t)s * DP];
    #pragma unroll
    for (int j = 0; j < 5; ++j){
      int c = lane + 64 * j;
      acc[j] += hr[c] + e0[c] + e1[c];
    }
  }
  #pragma unroll
  for (int j = 0; j < 5; ++j){
    int c = lane + 64 * j;
    u16 h = f2b(acc[j]);
    aggh[(size_t)v * DP + c] = h;
    aggl[(size_t)v * DP + c] = f2b(acc[j] - b2f(h));
  }
}

// ---------------- split-bf16 MFMA GEMM: C = A x Bt^T, A,Bt given as hi/lo planes ----------------
// OUTM: 0 -> fp32 C1 ; 1 -> split bf16 (C1=hi, C2=lo)
template<int KPAD, bool RELU, int OUTM>
__global__ __launch_bounds__(256) void k_gemm(const u16* __restrict__ Ah, const u16* __restrict__ Al,
    const u16* __restrict__ Bh, const u16* __restrict__ Bl,
    const float* __restrict__ bias, int bias_n,
    void* __restrict__ C1, void* __restrict__ C2, int ldc, int ccols,
    int M, int Nrows){
  __shared__ __attribute__((aligned(16))) u16 lAh[128 * 32];
  __shared__ __attribute__((aligned(16))) u16 lAl[128 * 32];
  __shared__ __attribute__((aligned(16))) u16 lBh[128 * 32];
  __shared__ __attribute__((aligned(16))) u16 lBl[128 * 32];
  const int tid = threadIdx.x;
  const int lane = tid & 63;
  const int wid = tid >> 6;
  const int gm0 = blockIdx.x * 128, gn0 = blockIdx.y * 128;
  const int wr = (wid >> 1) * 64, wc = (wid & 1) * 64;
  int ar1 = gm0 + (tid >> 2);       if (ar1 >= M) ar1 = M - 1;
  int ar2 = gm0 + 64 + (tid >> 2);  if (ar2 >= M) ar2 = M - 1;
  int br1 = gn0 + (tid >> 2);       if (br1 >= Nrows) br1 = Nrows - 1;
  int br2 = gn0 + 64 + (tid >> 2);  if (br2 >= Nrows) br2 = Nrows - 1;
  const int kb = (tid & 3) * 8;
  const int wbase = (tid & ~63) * 8;
  f32x4 acc[4][4] = {};
  for (int k0 = 0; k0 < KPAD; k0 += 32){
    __syncthreads();
    const size_t a1 = (size_t)ar1 * KPAD + k0 + kb, a2 = (size_t)ar2 * KPAD + k0 + kb;
    const size_t b1o = (size_t)br1 * KPAD + k0 + kb, b2o = (size_t)br2 * KPAD + k0 + kb;
    gl_lds16(Ah + a1, lAh + wbase);
    gl_lds16(Ah + a2, lAh + wbase + 2048);
    gl_lds16(Al + a1, lAl + wbase);
    gl_lds16(Al + a2, lAl + wbase + 2048);
    gl_lds16(Bh + b1o, lBh + wbase);
    gl_lds16(Bh + b2o, lBh + wbase + 2048);
    gl_lds16(Bl + b1o, lBl + wbase);
    gl_lds16(Bl + b2o, lBl + wbase + 2048);
    asm volatile("s_waitcnt vmcnt(0)" ::: "memory");
    __syncthreads();
    u16x8 afh[4], afl[4], bfh[4], bfl[4];
    #pragma unroll
    for (int m = 0; m < 4; ++m){
      int ro = (wr + m * 16 + (lane & 15)) * 32 + (lane >> 4) * 8;
      afh[m] = *(const u16x8*)&lAh[ro];
      afl[m] = *(const u16x8*)&lAl[ro];
    }
    #pragma unroll
    for (int n = 0; n < 4; ++n){
      int ro = (wc + n * 16 + (lane & 15)) * 32 + (lane >> 4) * 8;
      bfh[n] = *(const u16x8*)&lBh[ro];
      bfl[n] = *(const u16x8*)&lBl[ro];
    }
    #pragma unroll
    for (int m = 0; m < 4; ++m)
      #pragma unroll
      for (int n = 0; n < 4; ++n){
        acc[m][n] = mfma_bf16(afh[m], bfh[n], acc[m][n]);
        acc[m][n] = mfma_bf16(afh[m], bfl[n], acc[m][n]);
        acc[m][n] = mfma_bf16(afl[m], bfh[n], acc[m][n]);
      }
  }
  #pragma unroll
  for (int m = 0; m < 4; ++m){
    const int row0 = gm0 + wr + m * 16 + (lane >> 4) * 4;
    #pragma unroll
    for (int n = 0; n < 4; ++n){
      const int col = gn0 + wc + n * 16 + (lane & 15);
      if (col >= ccols) continue;
      const float bv = (col < bias_n) ? bias[col] : 0.f;
      #pragma unroll
      for (int r = 0; r < 4; ++r){
        const int row = row0 + r;
        if (row < M){
          float vv = acc[m][n][r] + bv;
          if (RELU) vv = fmaxf(vv, 0.f);
          if (OUTM == 0){
            ((float*)C1)[(size_t)row * ldc + col] = vv;
          } else {
            u16 h = f2b(vv);
            ((u16*)C1)[(size_t)row * ldc + col] = h;
            ((u16*)C2)[(size_t)row * ldc + col] = f2b(vv - b2f(h));
          }
        }
      }
    }
  }
}

// ---------------- BatchNorm ----------------
__global__ void k_bnstats(const float* __restrict__ h2, float* __restrict__ sums){
  int c = threadIdx.x;            // block = DP threads, c<300 active
  if (c >= D) return;
  int r0 = blockIdx.x * 250, r1 = r0 + 250;   // grid=200 -> 50000 rows
  float s = 0.f, q = 0.f;
  for (int r = r0; r < r1; ++r){
    float v = h2[(size_t)r * D + c];
    s += v; q += v * v;
  }
  atomicAdd(&sums[c], s);
  atomicAdd(&sums[DP + c], q);
}

template<bool LAST>
__global__ void k_bnapply(const float* h2, const float* __restrict__ sums,
    const float* __restrict__ gamma, const float* __restrict__ beta,
    float* __restrict__ hbf, float* outp){
  int r = blockIdx.x, c = threadIdx.x;   // block = DP
  float y = 0.f;
  if (c < D){
    float mu  = sums[c] * (1.f / NN);
    float var = sums[DP + c] * (1.f / NN) - mu * mu;
    float x = h2[(size_t)r * D + c];
    y = (x - mu) * rsqrtf(var + 1e-5f) * gamma[c] + beta[c];
    if (!LAST) y = fmaxf(y, 0.f);
  }
  if (LAST){ if (c < D) outp[(size_t)r * D + c] = y; }
  else hbf[(size_t)r * DP + c] = y;
}

extern "C" void kernel_launch(void* const* d_in, const int* in_sizes, int n_in,
                              void* d_out, int out_size, void* d_ws, size_t ws_size,
                              hipStream_t stream){
  (void)in_sizes; (void)n_in; (void)out_size; (void)ws_size;
  const int*   x    = (const int*)d_in[0];
  const int*   ei   = (const int*)d_in[1];
  const int*   ea   = (const int*)d_in[2];
  const float* xemb = (const float*)d_in[3];
  const float* eemb = (const float*)d_in[4];
  const float* W1   = (const float*)d_in[5];
  const float* b1   = (const float*)d_in[6];
  const float* W2   = (const float*)d_in[7];
  const float* b2   = (const float*)d_in[8];
  const float* gam  = (const float*)d_in[9];
  const float* bet  = (const float*)d_in[10];
  float* out = (float*)d_out;

  char* w = (char*)d_ws;
  size_t off = 0;
  auto alloc = [&](size_t b){ void* p = w + off; off += (b + 255) & ~(size_t)255; return p; };
  // hid (hi+lo, 128 MB) overlays hbf (fp32, 64 MB): live ranges disjoint
  // hbf: [bnapply_l .. agg_{l+1}] ; hid: [gemm1 .. gemm2] within each layer
  u16* hidh  = (u16*)alloc((size_t)NN * HP * 2);      // 64 MB
  u16* hidl  = (u16*)alloc((size_t)NN * HP * 2);      // 64 MB
  float* hbf = (float*)hidh;                          // alias (64 MB inside 128)
  u16* aggh  = (u16*)alloc((size_t)NN * DP * 2);      // 32 MB
  u16* aggl  = (u16*)alloc((size_t)NN * DP * 2);      // 32 MB
  u16* W1h   = (u16*)alloc((size_t)5 * HP * DP * 2);
  u16* W1l   = (u16*)alloc((size_t)5 * HP * DP * 2);
  u16* W2h   = (u16*)alloc((size_t)5 * DP * HP * 2);
  u16* W2l   = (u16*)alloc((size_t)5 * DP * HP * 2);
  int* rp    = (int*)alloc((NN + 1) * 4);
  int* cnt   = (int*)alloc((size_t)NN * 4);
  int* cur   = (int*)alloc((size_t)NN * 4);
  int* bsum  = (int*)alloc(64 * 4);
  int* pack  = (int*)alloc((size_t)NE * 4);
  float* sums= (float*)alloc(2 * DP * 4);
  float* h2  = out;   // reuse d_out as [NN][300] fp32 activation buffer

  hipMemsetAsync(cnt, 0, NN * 4, stream);
  k_count<<<NE / 256, 256, 0, stream>>>(ei, cnt);
  k_scan1<<<(NN + 1023) / 1024, 1024, 0, stream>>>(cnt, rp, bsum);
  k_scan2<<<1, 64, 0, stream>>>(bsum, (NN + 1023) / 1024);
  k_scan3<<<(NN + 255) / 256, 256, 0, stream>>>(rp, cur, bsum);
  k_fill<<<NE / 256, 256, 0, stream>>>(ei, ea, cur, pack);
  k_wconv<<<(5 * HP * DP) / 256, 256, 0, stream>>>(W1, W2, W1h, W1l, W2h, W2l);
  k_nodeemb<<<NN, DP, 0, stream>>>(x, xemb, hbf);

  for (int l = 0; l < 5; ++l){
    k_agg<<<(NN + 3) / 4, 256, 0, stream>>>(hbf, rp, pack, eemb + (size_t)l * 6 * D, aggh, aggl);
    k_gemm<DP, true, 1><<<dim3((NN + 127) / 128, HP / 128), 256, 0, stream>>>(
        aggh, aggl, W1h + (size_t)l * HP * DP, W1l + (size_t)l * HP * DP,
        b1 + l * 600, 600, hidh, hidl, HP, HP, NN, HP);
    k_gemm<HP, false, 0><<<dim3((NN + 127) / 128, 3), 256, 0, stream>>>(
        hidh, hidl, W2h + (size_t)l * DP * HP, W2l + (size_t)l * DP * HP,
        b2 + l * D, D, h2, nullptr, D, D, NN, DP);
    hipMemsetAsync(sums, 0, 2 * DP * 4, stream);
    k_bnstats<<<200, DP, 0, stream>>>(h2, sums);
    if (l < 4) k_bnapply<false><<<NN, DP, 0, stream>>>(h2, sums, gam + l * D, bet + l * D, hbf, nullptr);
    else       k_bnapply<true ><<<NN, DP, 0, stream>>>(h2, sums, gam + l * D, bet + l * D, nullptr, out);
  }
}

// Round 3
// 1540.581 us; speedup vs baseline: 1.5941x; 1.5941x over previous
//
#include <hip/hip_runtime.h>
#include <hip/hip_bf16.h>

typedef unsigned short u16;
typedef _Float16 f16;
typedef f16 f16x8 __attribute__((ext_vector_type(8)));
typedef u16 u16x8 __attribute__((ext_vector_type(8)));
typedef float f32x4 __attribute__((ext_vector_type(4)));

#define NN 50000
#define NE 800000
#define D  300
#define DP 320   // padded feature dim
#define HP 640   // padded hidden dim

__device__ __forceinline__ float h2f(u16 u){ f16 h = __builtin_bit_cast(f16, u); return (float)h; }
__device__ __forceinline__ u16 f2h(float f){ f16 h = (f16)f; return __builtin_bit_cast(u16, h); }

__device__ __forceinline__ void gl_lds16(const void* g, void* l){
  __builtin_amdgcn_global_load_lds((const __attribute__((address_space(1))) unsigned int*)g,
                                   (__attribute__((address_space(3))) unsigned int*)l, 16, 0, 0);
}

__device__ __forceinline__ f32x4 mfma_f16(u16x8 a, u16x8 b, f32x4 c){
  return __builtin_amdgcn_mfma_f32_16x16x32_f16(__builtin_bit_cast(f16x8, a),
                                                __builtin_bit_cast(f16x8, b), c, 0, 0, 0);
}

// ---------------- CSR build (by dst) ----------------
__global__ void k_count(const int* __restrict__ ei, int* __restrict__ cnt){
  int e = blockIdx.x * 256 + threadIdx.x;
  if (e < NE) atomicAdd(&cnt[ei[NE + e]], 1);
}

__global__ void k_scan1(const int* __restrict__ cnt, int* __restrict__ rp, int* __restrict__ bsum){
  __shared__ int s[1024];
  int i = blockIdx.x * 1024 + threadIdx.x;
  int v = (i < NN) ? cnt[i] : 0;
  s[threadIdx.x] = v;
  __syncthreads();
  for (int off = 1; off < 1024; off <<= 1){
    int t = (threadIdx.x >= off) ? s[threadIdx.x - off] : 0;
    __syncthreads();
    s[threadIdx.x] += t;
    __syncthreads();
  }
  if (i < NN) rp[i] = s[threadIdx.x] - v;
  if (threadIdx.x == 1023) bsum[blockIdx.x] = s[1023];
}

__global__ void k_scan2(int* __restrict__ bsum, int nb){
  __shared__ int s[64];
  int v = (threadIdx.x < nb) ? bsum[threadIdx.x] : 0;
  s[threadIdx.x] = v; __syncthreads();
  for (int off = 1; off < 64; off <<= 1){
    int t = (threadIdx.x >= off) ? s[threadIdx.x - off] : 0;
    __syncthreads();
    s[threadIdx.x] += t;
    __syncthreads();
  }
  if (threadIdx.x < nb) bsum[threadIdx.x] = s[threadIdx.x] - v;
}

__global__ void k_scan3(int* __restrict__ rp, int* __restrict__ cur, const int* __restrict__ bsum){
  int i = blockIdx.x * 256 + threadIdx.x;
  if (i < NN){ int v = rp[i] + bsum[i >> 10]; rp[i] = v; cur[i] = v; }
  if (i == 0) rp[NN] = NE;
}

__global__ void k_fill(const int* __restrict__ ei, const int* __restrict__ ea,
                       int* __restrict__ cur, int* __restrict__ pack){
  int e = blockIdx.x * 256 + threadIdx.x;
  if (e >= NE) return;
  int d = ei[NE + e];
  int pos = atomicAdd(&cur[d], 1);
  // src fits in 16 bits; combo = a0*3+a1 in [0,9)
  pack[pos] = ei[e] | ((ea[2*e] * 3 + ea[2*e + 1]) << 16);
}

// ---------------- weight transpose + pad -> fp16 ----------------
// W1t: [5][HP][DP] (n-major, contiguous K) ; W2t: [5][DP][HP]
__global__ void k_wconv(const float* __restrict__ W1, const float* __restrict__ W2,
                        u16* __restrict__ W1t, u16* __restrict__ W2t){
  int i = blockIdx.x * 256 + threadIdx.x;
  {
    int l = i / (HP * DP); int rem = i % (HP * DP); int n = rem / DP, k = rem % DP;
    float v = (n < 600 && k < D) ? W1[((size_t)l * D + k) * 600 + n] : 0.f;
    W1t[i] = f2h(v);
  }
  {
    int l = i / (DP * HP); int rem = i % (DP * HP); int n = rem / HP, k = rem % HP;
    float v = (n < D && k < 600) ? W2[((size_t)l * 600 + k) * D + n] : 0.f;
    W2t[i] = f2h(v);
  }
}

// ---------------- node embedding -> fp16 padded ----------------
__global__ void k_nodeemb(const int* __restrict__ x, const float* __restrict__ xemb, u16* __restrict__ hb){
  int v = blockIdx.x, c = threadIdx.x;  // block = DP threads
  float y = 0.f;
  if (c < D){
    int a = x[2*v], b = x[2*v + 1];
    y = xemb[(size_t)a * D + c] + xemb[(size_t)b * D + c];
  }
  hb[(size_t)v * DP + c] = f2h(y);
}

// ---------------- per-layer aggregation: one wave per node, fp16 gather ----------------
__global__ __launch_bounds__(256) void k_agg(const u16* __restrict__ hb, const int* __restrict__ rp,
    const int* __restrict__ pack, const float* __restrict__ eemb, u16* __restrict__ agg){
  __shared__ float ec[10 * DP];   // combined edge-emb: slots 0..8 = e[a0]+e[a1], slot 9 = e[4]+e[0] (self)
  for (int i = threadIdx.x; i < 10 * DP; i += 256){
    int t = i / DP, c = i % DP;
    float v = 0.f;
    if (c < D){
      int a0 = (t == 9) ? 4 : (t / 3), a1 = (t == 9) ? 0 : (t % 3);
      v = eemb[a0 * D + c] + eemb[a1 * D + c];
    }
    ec[i] = v;
  }
  __syncthreads();
  int wid = threadIdx.x >> 6, lane = threadIdx.x & 63;
  int v = blockIdx.x * 4 + wid;
  if (v >= NN) return;
  float acc[5];
  const u16* hv = hb + (size_t)v * DP;
  #pragma unroll
  for (int j = 0; j < 5; ++j){
    int c = lane + 64 * j;
    acc[j] = h2f(hv[c]) + ec[9 * DP + c];
  }
  int p = rp[v], p1 = rp[v + 1];
  for (; p + 2 <= p1; p += 2){
    int pk0 = pack[p], pk1 = pack[p + 1];
    const u16* h0 = hb + (size_t)(pk0 & 0xFFFF) * DP;
    const u16* h1 = hb + (size_t)(pk1 & 0xFFFF) * DP;
    const float* e0 = &ec[(pk0 >> 16) * DP];
    const float* e1 = &ec[(pk1 >> 16) * DP];
    u16 t0[5], t1[5];
    #pragma unroll
    for (int j = 0; j < 5; ++j){ int c = lane + 64 * j; t0[j] = h0[c]; t1[j] = h1[c]; }
    #pragma unroll
    for (int j = 0; j < 5; ++j){
      int c = lane + 64 * j;
      acc[j] += (h2f(t0[j]) + e0[c]) + (h2f(t1[j]) + e1[c]);
    }
  }
  if (p < p1){
    int pk0 = pack[p];
    const u16* h0 = hb + (size_t)(pk0 & 0xFFFF) * DP;
    const float* e0 = &ec[(pk0 >> 16) * DP];
    #pragma unroll
    for (int j = 0; j < 5; ++j){
      int c = lane + 64 * j;
      acc[j] += h2f(h0[c]) + e0[c];
    }
  }
  #pragma unroll
  for (int j = 0; j < 5; ++j) agg[(size_t)v * DP + lane + 64 * j] = f2h(acc[j]);
}

// ---------------- fp16 MFMA GEMM: C = A x Bt^T ----------------
// OUTM: 0 -> fp32 C ; 1 -> fp16 C
template<int KPAD, bool RELU, int OUTM>
__global__ __launch_bounds__(256) void k_gemm(const u16* __restrict__ A, const u16* __restrict__ Bt,
    const float* __restrict__ bias, int bias_n,
    void* __restrict__ C, int ldc, int ccols, int M, int Nrows){
  __shared__ __attribute__((aligned(16))) u16 lA[128 * 32];
  __shared__ __attribute__((aligned(16))) u16 lB[128 * 32];
  const int tid = threadIdx.x;
  const int lane = tid & 63;
  const int wid = tid >> 6;
  const int gm0 = blockIdx.x * 128, gn0 = blockIdx.y * 128;
  const int wr = (wid >> 1) * 64, wc = (wid & 1) * 64;
  int ar1 = gm0 + (tid >> 2);       if (ar1 >= M) ar1 = M - 1;
  int ar2 = gm0 + 64 + (tid >> 2);  if (ar2 >= M) ar2 = M - 1;
  int br1 = gn0 + (tid >> 2);       if (br1 >= Nrows) br1 = Nrows - 1;
  int br2 = gn0 + 64 + (tid >> 2);  if (br2 >= Nrows) br2 = Nrows - 1;
  const int kb = (tid & 3) * 8;
  const int wbase = (tid & ~63) * 8;
  f32x4 acc[4][4] = {};
  for (int k0 = 0; k0 < KPAD; k0 += 32){
    __syncthreads();
    gl_lds16(A  + (size_t)ar1 * KPAD + k0 + kb, lA + wbase);
    gl_lds16(A  + (size_t)ar2 * KPAD + k0 + kb, lA + wbase + 2048);
    gl_lds16(Bt + (size_t)br1 * KPAD + k0 + kb, lB + wbase);
    gl_lds16(Bt + (size_t)br2 * KPAD + k0 + kb, lB + wbase + 2048);
    asm volatile("s_waitcnt vmcnt(0)" ::: "memory");
    __syncthreads();
    u16x8 af[4], bfr[4];
    #pragma unroll
    for (int m = 0; m < 4; ++m) af[m]  = *(const u16x8*)&lA[(wr + m * 16 + (lane & 15)) * 32 + (lane >> 4) * 8];
    #pragma unroll
    for (int n = 0; n < 4; ++n) bfr[n] = *(const u16x8*)&lB[(wc + n * 16 + (lane & 15)) * 32 + (lane >> 4) * 8];
    #pragma unroll
    for (int m = 0; m < 4; ++m)
      #pragma unroll
      for (int n = 0; n < 4; ++n)
        acc[m][n] = mfma_f16(af[m], bfr[n], acc[m][n]);
  }
  #pragma unroll
  for (int m = 0; m < 4; ++m){
    const int row0 = gm0 + wr + m * 16 + (lane >> 4) * 4;
    #pragma unroll
    for (int n = 0; n < 4; ++n){
      const int col = gn0 + wc + n * 16 + (lane & 15);
      if (col >= ccols) continue;
      const float bv = (col < bias_n) ? bias[col] : 0.f;
      #pragma unroll
      for (int r = 0; r < 4; ++r){
        const int row = row0 + r;
        if (row < M){
          float vv = acc[m][n][r] + bv;
          if (RELU) vv = fmaxf(vv, 0.f);
          if (OUTM == 0) ((float*)C)[(size_t)row * ldc + col] = vv;
          else           ((u16*)C)[(size_t)row * ldc + col] = f2h(vv);
        }
      }
    }
  }
}

// ---------------- BatchNorm ----------------
__global__ void k_bnstats(const float* __restrict__ h2, float* __restrict__ sums){
  int c = threadIdx.x;            // block = DP threads, c<300 active
  if (c >= D) return;
  int r0 = blockIdx.x * 250, r1 = r0 + 250;   // grid=200 -> 50000 rows
  float s = 0.f, q = 0.f;
  for (int r = r0; r < r1; ++r){
    float v = h2[(size_t)r * D + c];
    s += v; q += v * v;
  }
  atomicAdd(&sums[c], s);
  atomicAdd(&sums[DP + c], q);
}

template<bool LAST>
__global__ void k_bnapply(const float* h2, const float* __restrict__ sums,
    const float* __restrict__ gamma, const float* __restrict__ beta,
    u16* __restrict__ hb, float* outp){
  int r = blockIdx.x, c = threadIdx.x;   // block = DP
  float y = 0.f;
  if (c < D){
    float mu  = sums[c] * (1.f / NN);
    float var = sums[DP + c] * (1.f / NN) - mu * mu;
    float x = h2[(size_t)r * D + c];
    float s = var + 1e-5f;
    float inv = rsqrtf(s);
    inv = inv * (1.5f - 0.5f * s * inv * inv);   // Newton: full fp32 accuracy
    y = (x - mu) * inv * gamma[c] + beta[c];
    if (!LAST) y = fmaxf(y, 0.f);
  }
  if (LAST){ if (c < D) outp[(size_t)r * D + c] = y; }
  else hb[(size_t)r * DP + c] = f2h(y);    // pad cols -> 0
}

extern "C" void kernel_launch(void* const* d_in, const int* in_sizes, int n_in,
                              void* d_out, int out_size, void* d_ws, size_t ws_size,
                              hipStream_t stream){
  (void)in_sizes; (void)n_in; (void)out_size; (void)ws_size;
  const int*   x    = (const int*)d_in[0];
  const int*   ei   = (const int*)d_in[1];
  const int*   ea   = (const int*)d_in[2];
  const float* xemb = (const float*)d_in[3];
  const float* eemb = (const float*)d_in[4];
  const float* W1   = (const float*)d_in[5];
  const float* b1   = (const float*)d_in[6];
  const float* W2   = (const float*)d_in[7];
  const float* b2   = (const float*)d_in[8];
  const float* gam  = (const float*)d_in[9];
  const float* bet  = (const float*)d_in[10];
  float* out = (float*)d_out;

  char* w = (char*)d_ws;
  size_t off = 0;
  auto alloc = [&](size_t b){ void* p = w + off; off += (b + 255) & ~(size_t)255; return p; };
  // hid (fp16, 64 MB) overlays hb (fp16, 32 MB): live ranges disjoint
  // hb: [bnapply_l .. agg_{l+1}] ; hid: [gemm1 .. gemm2] within each layer
  u16* hid   = (u16*)alloc((size_t)NN * HP * 2);      // 64 MB
  u16* hb    = hid;                                    // alias (32 MB inside 64)
  u16* aggb  = (u16*)alloc((size_t)NN * DP * 2);      // 32 MB
  u16* W1t   = (u16*)alloc((size_t)5 * HP * DP * 2);  // 2 MB
  u16* W2t   = (u16*)alloc((size_t)5 * DP * HP * 2);  // 2 MB
  int* rp    = (int*)alloc((NN + 1) * 4);
  int* cnt   = (int*)alloc((size_t)NN * 4);
  int* cur   = (int*)alloc((size_t)NN * 4);
  int* bsum  = (int*)alloc(64 * 4);
  int* pack  = (int*)alloc((size_t)NE * 4);
  float* sums= (float*)alloc(2 * DP * 4);
  float* h2  = out;   // reuse d_out as [NN][300] fp32 activation buffer

  hipMemsetAsync(cnt, 0, NN * 4, stream);
  k_count<<<NE / 256, 256, 0, stream>>>(ei, cnt);
  k_scan1<<<(NN + 1023) / 1024, 1024, 0, stream>>>(cnt, rp, bsum);
  k_scan2<<<1, 64, 0, stream>>>(bsum, (NN + 1023) / 1024);
  k_scan3<<<(NN + 255) / 256, 256, 0, stream>>>(rp, cur, bsum);
  k_fill<<<NE / 256, 256, 0, stream>>>(ei, ea, cur, pack);
  k_wconv<<<(5 * HP * DP) / 256, 256, 0, stream>>>(W1, W2, W1t, W2t);
  k_nodeemb<<<NN, DP, 0, stream>>>(x, xemb, hb);

  for (int l = 0; l < 5; ++l){
    k_agg<<<(NN + 3) / 4, 256, 0, stream>>>(hb, rp, pack, eemb + (size_t)l * 6 * D, aggb);
    k_gemm<DP, true, 1><<<dim3((NN + 127) / 128, HP / 128), 256, 0, stream>>>(
        aggb, W1t + (size_t)l * HP * DP, b1 + l * 600, 600, hid, HP, HP, NN, HP);
    k_gemm<HP, false, 0><<<dim3((NN + 127) / 128, 3), 256, 0, stream>>>(
        hid, W2t + (size_t)l * DP * HP, b2 + l * D, D, h2, D, D, NN, DP);
    hipMemsetAsync(sums, 0, 2 * DP * 4, stream);
    k_bnstats<<<200, DP, 0, stream>>>(h2, sums);
    if (l < 4) k_bnapply<false><<<NN, DP, 0, stream>>>(h2, sums, gam + l * D, bet + l * D, hb, nullptr);
    else       k_bnapply<true ><<<NN, DP, 0, stream>>>(h2, sums, gam + l * D, bet + l * D, nullptr, out);
  }
}

// Round 4
// 1535.549 us; speedup vs baseline: 1.5994x; 1.0033x over previous
//
#include <hip/hip_runtime.h>
#include <hip/hip_bf16.h>

typedef unsigned short u16;
typedef _Float16 f16;
typedef f16 f16x8 __attribute__((ext_vector_type(8)));
typedef f16 half2t __attribute__((ext_vector_type(2)));
typedef u16 u16x8 __attribute__((ext_vector_type(8)));
typedef float f32x4 __attribute__((ext_vector_type(4)));

#define NN 50000
#define NE 800000
#define D  300
#define DP 320   // padded feature dim
#define HP 640   // padded hidden dim

__device__ __forceinline__ float h2f(u16 u){ f16 h = __builtin_bit_cast(f16, u); return (float)h; }
__device__ __forceinline__ u16 f2h(float f){ f16 h = (f16)f; return __builtin_bit_cast(u16, h); }
__device__ __forceinline__ float hlo(unsigned u){ half2t h = __builtin_bit_cast(half2t, u); return (float)h.x; }
__device__ __forceinline__ float hhi(unsigned u){ half2t h = __builtin_bit_cast(half2t, u); return (float)h.y; }
__device__ __forceinline__ unsigned packh(float x, float y){ half2t h; h.x = (f16)x; h.y = (f16)y; return __builtin_bit_cast(unsigned, h); }

__device__ __forceinline__ void gl_lds16(const void* g, void* l){
  __builtin_amdgcn_global_load_lds((const __attribute__((address_space(1))) unsigned int*)g,
                                   (__attribute__((address_space(3))) unsigned int*)l, 16, 0, 0);
}

__device__ __forceinline__ f32x4 mfma_f16(u16x8 a, u16x8 b, f32x4 c){
  return __builtin_amdgcn_mfma_f32_16x16x32_f16(__builtin_bit_cast(f16x8, a),
                                                __builtin_bit_cast(f16x8, b), c, 0, 0, 0);
}

// ---------------- CSR build (by dst) + per-(dst,combo) counts ----------------
__global__ void k_count(const int* __restrict__ ei, const int* __restrict__ ea,
                        int* __restrict__ cnt, int* __restrict__ ccnt){
  int e = blockIdx.x * 256 + threadIdx.x;
  if (e < NE){
    int d = ei[NE + e];
    atomicAdd(&cnt[d], 1);
    int t = ea[2*e] * 3 + ea[2*e + 1];     // attrs in [0,3)
    atomicAdd(&ccnt[d * 12 + t], 1);
  }
}

__global__ void k_scan1(const int* __restrict__ cnt, int* __restrict__ rp, int* __restrict__ bsum){
  __shared__ int s[1024];
  int i = blockIdx.x * 1024 + threadIdx.x;
  int v = (i < NN) ? cnt[i] : 0;
  s[threadIdx.x] = v;
  __syncthreads();
  for (int off = 1; off < 1024; off <<= 1){
    int t = (threadIdx.x >= off) ? s[threadIdx.x - off] : 0;
    __syncthreads();
    s[threadIdx.x] += t;
    __syncthreads();
  }
  if (i < NN) rp[i] = s[threadIdx.x] - v;
  if (threadIdx.x == 1023) bsum[blockIdx.x] = s[1023];
}

__global__ void k_scan2(int* __restrict__ bsum, int nb){
  __shared__ int s[64];
  int v = (threadIdx.x < nb) ? bsum[threadIdx.x] : 0;
  s[threadIdx.x] = v; __syncthreads();
  for (int off = 1; off < 64; off <<= 1){
    int t = (threadIdx.x >= off) ? s[threadIdx.x - off] : 0;
    __syncthreads();
    s[threadIdx.x] += t;
    __syncthreads();
  }
  if (threadIdx.x < nb) bsum[threadIdx.x] = s[threadIdx.x] - v;
}

__global__ void k_scan3(int* __restrict__ rp, int* __restrict__ cur, const int* __restrict__ bsum){
  int i = blockIdx.x * 256 + threadIdx.x;
  if (i < NN){ int v = rp[i] + bsum[i >> 10]; rp[i] = v; cur[i] = v; }
  if (i == 0) rp[NN] = NE;
}

__global__ void k_fill(const int* __restrict__ ei, int* __restrict__ cur, int* __restrict__ pack){
  int e = blockIdx.x * 256 + threadIdx.x;
  if (e >= NE) return;
  int d = ei[NE + e];
  int pos = atomicAdd(&cur[d], 1);
  pack[pos] = ei[e];                       // src only
}

// ---------------- weight transpose + pad -> fp16 ----------------
__global__ void k_wconv(const float* __restrict__ W1, const float* __restrict__ W2,
                        u16* __restrict__ W1t, u16* __restrict__ W2t){
  int i = blockIdx.x * 256 + threadIdx.x;
  {
    int l = i / (HP * DP); int rem = i % (HP * DP); int n = rem / DP, k = rem % DP;
    float v = (n < 600 && k < D) ? W1[((size_t)l * D + k) * 600 + n] : 0.f;
    W1t[i] = f2h(v);
  }
  {
    int l = i / (DP * HP); int rem = i % (DP * HP); int n = rem / HP, k = rem % HP;
    float v = (n < D && k < 600) ? W2[((size_t)l * 600 + k) * D + n] : 0.f;
    W2t[i] = f2h(v);
  }
}

// ---------------- node embedding -> fp16 padded ----------------
__global__ void k_nodeemb(const int* __restrict__ x, const float* __restrict__ xemb, u16* __restrict__ hb){
  int v = blockIdx.x, c = threadIdx.x;  // block = DP threads
  float y = 0.f;
  if (c < D){
    int a = x[2*v], b = x[2*v + 1];
    y = xemb[(size_t)a * D + c] + xemb[(size_t)b * D + c];
  }
  hb[(size_t)v * DP + c] = f2h(y);
}

// ---------------- per-layer aggregation: one wave per node ----------------
// agg[v] = h[v] + sum_{e->v} h[src] + w0*e0 + w1*e1 + w2*e2 + e4   (ee via combo counts)
__global__ __launch_bounds__(256) void k_agg(const u16* __restrict__ hb, const int* __restrict__ rp,
    const int* __restrict__ pack, const int* __restrict__ ccnt,
    const float* __restrict__ eemb, u16* __restrict__ agg){
  __shared__ float se[4 * DP];   // rows e0,e1,e2,e4 (fp32)
  for (int i = threadIdx.x; i < 4 * DP; i += 256){
    int t = i / DP, c = i % DP;
    int row = (t == 3) ? 4 : t;
    se[i] = (c < D) ? eemb[row * D + c] : 0.f;
  }
  __syncthreads();
  const int wid = threadIdx.x >> 6, lane = threadIdx.x & 63;
  const int v = blockIdx.x * 4 + wid;
  if (v >= NN) return;
  const char* __restrict__ hbb = (const char*)hb;
  const unsigned lo8 = (unsigned)lane * 8u;          // cols 4l..4l+3
  const unsigned lo4 = 512u + (unsigned)lane * 4u;   // cols 256+2l, 257+2l (lanes<32)
  float a0, a1, a2, a3, a4 = 0.f, a5 = 0.f;
  {
    unsigned off = (unsigned)v * 640u;
    uint2 u = *(const uint2*)(hbb + off + lo8);
    a0 = hlo(u.x); a1 = hhi(u.x); a2 = hlo(u.y); a3 = hhi(u.y);
    if (lane < 32){ unsigned uw = *(const unsigned*)(hbb + off + lo4); a4 = hlo(uw); a5 = hhi(uw); }
  }
  int p = rp[v];
  const int pe = rp[v + 1];
  for (; p + 2 <= pe; p += 2){
    unsigned off0 = (unsigned)pack[p] * 640u;
    unsigned off1 = (unsigned)pack[p + 1] * 640u;
    uint2 u0 = *(const uint2*)(hbb + off0 + lo8);
    uint2 u1 = *(const uint2*)(hbb + off1 + lo8);
    unsigned w0v = 0, w1v = 0;
    if (lane < 32){
      w0v = *(const unsigned*)(hbb + off0 + lo4);
      w1v = *(const unsigned*)(hbb + off1 + lo4);
    }
    a0 += hlo(u0.x) + hlo(u1.x);
    a1 += hhi(u0.x) + hhi(u1.x);
    a2 += hlo(u0.y) + hlo(u1.y);
    a3 += hhi(u0.y) + hhi(u1.y);
    a4 += hlo(w0v) + hlo(w1v);
    a5 += hhi(w0v) + hhi(w1v);
  }
  if (p < pe){
    unsigned off0 = (unsigned)pack[p] * 640u;
    uint2 u0 = *(const uint2*)(hbb + off0 + lo8);
    a0 += hlo(u0.x); a1 += hhi(u0.x); a2 += hlo(u0.y); a3 += hhi(u0.y);
    if (lane < 32){ unsigned w0v = *(const unsigned*)(hbb + off0 + lo4); a4 += hlo(w0v); a5 += hhi(w0v); }
  }
  // combo counts -> base-row weights  (w0 gets +1 from self-loop's e0; e4 weight 1)
  const int* cc = ccnt + (size_t)v * 12;
  int4 cA = *(const int4*)cc;          // c0..c3
  int4 cB = *(const int4*)(cc + 4);    // c4..c7
  int c8 = cc[8];
  float w0f = (float)(2 * cA.x + cA.y + cA.z + cA.w + cB.z + 1);
  float w1f = (float)(cA.y + cA.w + 2 * cB.x + cB.y + cB.w);
  float w2f = (float)(cA.z + cB.y + cB.z + cB.w + 2 * c8);
  {
    const float4 e0v = *(const float4*)&se[0 * DP + 4 * lane];
    const float4 e1v = *(const float4*)&se[1 * DP + 4 * lane];
    const float4 e2v = *(const float4*)&se[2 * DP + 4 * lane];
    const float4 e4v = *(const float4*)&se[3 * DP + 4 * lane];
    a0 += w0f * e0v.x + w1f * e1v.x + w2f * e2v.x + e4v.x;
    a1 += w0f * e0v.y + w1f * e1v.y + w2f * e2v.y + e4v.y;
    a2 += w0f * e0v.z + w1f * e1v.z + w2f * e2v.z + e4v.z;
    a3 += w0f * e0v.w + w1f * e1v.w + w2f * e2v.w + e4v.w;
  }
  char* ab = (char*)agg;
  unsigned oo = (unsigned)v * 640u;
  uint2 st; st.x = packh(a0, a1); st.y = packh(a2, a3);
  *(uint2*)(ab + oo + lo8) = st;
  if (lane < 32){
    int cI = 256 + 2 * lane;
    a4 += w0f * se[0 * DP + cI]     + w1f * se[1 * DP + cI]     + w2f * se[2 * DP + cI]     + se[3 * DP + cI];
    a5 += w0f * se[0 * DP + cI + 1] + w1f * se[1 * DP + cI + 1] + w2f * se[2 * DP + cI + 1] + se[3 * DP + cI + 1];
    *(unsigned*)(ab + oo + lo4) = packh(a4, a5);
  }
}

// ---------------- fp16 MFMA GEMM: C = A x Bt^T ----------------
// OUTM: 0 -> fp32 C (+ fused BN stats via atomics) ; 1 -> fp16 C
template<int KPAD, bool RELU, int OUTM>
__global__ __launch_bounds__(256) void k_gemm(const u16* __restrict__ A, const u16* __restrict__ Bt,
    const float* __restrict__ bias, int bias_n,
    void* __restrict__ C, int ldc, int ccols, int M, int Nrows,
    float* __restrict__ sums){
  __shared__ __attribute__((aligned(16))) u16 lA[128 * 32];
  __shared__ __attribute__((aligned(16))) u16 lB[128 * 32];
  const int tid = threadIdx.x;
  const int lane = tid & 63;
  const int wid = tid >> 6;
  const int gm0 = blockIdx.x * 128, gn0 = blockIdx.y * 128;
  const int wr = (wid >> 1) * 64, wc = (wid & 1) * 64;
  int ar1 = gm0 + (tid >> 2);       if (ar1 >= M) ar1 = M - 1;
  int ar2 = gm0 + 64 + (tid >> 2);  if (ar2 >= M) ar2 = M - 1;
  int br1 = gn0 + (tid >> 2);       if (br1 >= Nrows) br1 = Nrows - 1;
  int br2 = gn0 + 64 + (tid >> 2);  if (br2 >= Nrows) br2 = Nrows - 1;
  const int kb = (tid & 3) * 8;
  const int wbase = (tid & ~63) * 8;
  f32x4 acc[4][4] = {};
  for (int k0 = 0; k0 < KPAD; k0 += 32){
    __syncthreads();
    gl_lds16(A  + (size_t)ar1 * KPAD + k0 + kb, lA + wbase);
    gl_lds16(A  + (size_t)ar2 * KPAD + k0 + kb, lA + wbase + 2048);
    gl_lds16(Bt + (size_t)br1 * KPAD + k0 + kb, lB + wbase);
    gl_lds16(Bt + (size_t)br2 * KPAD + k0 + kb, lB + wbase + 2048);
    asm volatile("s_waitcnt vmcnt(0)" ::: "memory");
    __syncthreads();
    u16x8 af[4], bfr[4];
    #pragma unroll
    for (int m = 0; m < 4; ++m) af[m]  = *(const u16x8*)&lA[(wr + m * 16 + (lane & 15)) * 32 + (lane >> 4) * 8];
    #pragma unroll
    for (int n = 0; n < 4; ++n) bfr[n] = *(const u16x8*)&lB[(wc + n * 16 + (lane & 15)) * 32 + (lane >> 4) * 8];
    #pragma unroll
    for (int m = 0; m < 4; ++m)
      #pragma unroll
      for (int n = 0; n < 4; ++n)
        acc[m][n] = mfma_f16(af[m], bfr[n], acc[m][n]);
  }
  float sn[4] = {0.f, 0.f, 0.f, 0.f}, qn[4] = {0.f, 0.f, 0.f, 0.f};
  #pragma unroll
  for (int m = 0; m < 4; ++m){
    const int row0 = gm0 + wr + m * 16 + (lane >> 4) * 4;
    #pragma unroll
    for (int n = 0; n < 4; ++n){
      const int col = gn0 + wc + n * 16 + (lane & 15);
      if (col >= ccols) continue;
      const float bv = (col < bias_n) ? bias[col] : 0.f;
      #pragma unroll
      for (int r = 0; r < 4; ++r){
        const int row = row0 + r;
        if (row < M){
          float vv = acc[m][n][r] + bv;
          if (RELU) vv = fmaxf(vv, 0.f);
          if (OUTM == 0){
            ((float*)C)[(size_t)row * ldc + col] = vv;
            sn[n] += vv; qn[n] += vv * vv;
          } else {
            ((u16*)C)[(size_t)row * ldc + col] = f2h(vv);
          }
        }
      }
    }
  }
  if (OUTM == 0){
    #pragma unroll
    for (int n = 0; n < 4; ++n){
      const int col = gn0 + wc + n * 16 + (lane & 15);
      float s = sn[n], q = qn[n];
      s += __shfl_xor(s, 16); q += __shfl_xor(q, 16);
      s += __shfl_xor(s, 32); q += __shfl_xor(q, 32);
      if (col < ccols && (lane >> 4) == 0){
        atomicAdd(&sums[col], s);
        atomicAdd(&sums[DP + col], q);
      }
    }
  }
}

// ---------------- BatchNorm apply ----------------
template<bool LAST>
__global__ void k_bnapply(const float* h2, const float* __restrict__ sums,
    const float* __restrict__ gamma, const float* __restrict__ beta,
    u16* __restrict__ hb, float* outp){
  int r = blockIdx.x, c = threadIdx.x;   // block = DP
  float y = 0.f;
  if (c < D){
    float mu  = sums[c] * (1.f / NN);
    float var = sums[DP + c] * (1.f / NN) - mu * mu;
    float x = h2[(size_t)r * D + c];
    float s = var + 1e-5f;
    float inv = rsqrtf(s);
    inv = inv * (1.5f - 0.5f * s * inv * inv);   // Newton: full fp32 accuracy
    y = (x - mu) * inv * gamma[c] + beta[c];
    if (!LAST) y = fmaxf(y, 0.f);
  }
  if (LAST){ if (c < D) outp[(size_t)r * D + c] = y; }
  else hb[(size_t)r * DP + c] = f2h(y);    // pad cols -> 0
}

extern "C" void kernel_launch(void* const* d_in, const int* in_sizes, int n_in,
                              void* d_out, int out_size, void* d_ws, size_t ws_size,
                              hipStream_t stream){
  (void)in_sizes; (void)n_in; (void)out_size; (void)ws_size;
  const int*   x    = (const int*)d_in[0];
  const int*   ei   = (const int*)d_in[1];
  const int*   ea   = (const int*)d_in[2];
  const float* xemb = (const float*)d_in[3];
  const float* eemb = (const float*)d_in[4];
  const float* W1   = (const float*)d_in[5];
  const float* b1   = (const float*)d_in[6];
  const float* W2   = (const float*)d_in[7];
  const float* b2   = (const float*)d_in[8];
  const float* gam  = (const float*)d_in[9];
  const float* bet  = (const float*)d_in[10];
  float* out = (float*)d_out;

  char* w = (char*)d_ws;
  size_t off = 0;
  auto alloc = [&](size_t b){ void* p = w + off; off += (b + 255) & ~(size_t)255; return p; };
  // hid (fp16, 64 MB) overlays hb (fp16, 32 MB): live ranges disjoint within a layer
  u16* hid   = (u16*)alloc((size_t)NN * HP * 2);      // 64 MB
  u16* hb    = hid;                                    // alias (32 MB inside 64)
  u16* aggb  = (u16*)alloc((size_t)NN * DP * 2);      // 32 MB
  u16* W1t   = (u16*)alloc((size_t)5 * HP * DP * 2);  // 2 MB
  u16* W2t   = (u16*)alloc((size_t)5 * DP * HP * 2);  // 2 MB
  int* rp    = (int*)alloc((NN + 1) * 4);
  int* cnt   = (int*)alloc((size_t)NN * 4);
  int* cur   = (int*)alloc((size_t)NN * 4);
  int* bsum  = (int*)alloc(64 * 4);
  int* pack  = (int*)alloc((size_t)NE * 4);
  int* ccnt  = (int*)alloc((size_t)NN * 12 * 4);      // 2.4 MB
  float* sums= (float*)alloc(2 * DP * 4);
  float* h2  = out;   // reuse d_out as [NN][300] fp32 activation buffer

  hipMemsetAsync(cnt, 0, NN * 4, stream);
  hipMemsetAsync(ccnt, 0, (size_t)NN * 12 * 4, stream);
  k_count<<<NE / 256, 256, 0, stream>>>(ei, ea, cnt, ccnt);
  k_scan1<<<(NN + 1023) / 1024, 1024, 0, stream>>>(cnt, rp, bsum);
  k_scan2<<<1, 64, 0, stream>>>(bsum, (NN + 1023) / 1024);
  k_scan3<<<(NN + 255) / 256, 256, 0, stream>>>(rp, cur, bsum);
  k_fill<<<NE / 256, 256, 0, stream>>>(ei, cur, pack);
  k_wconv<<<(5 * HP * DP) / 256, 256, 0, stream>>>(W1, W2, W1t, W2t);
  k_nodeemb<<<NN, DP, 0, stream>>>(x, xemb, hb);

  for (int l = 0; l < 5; ++l){
    k_agg<<<(NN + 3) / 4, 256, 0, stream>>>(hb, rp, pack, ccnt, eemb + (size_t)l * 6 * D, aggb);
    k_gemm<DP, true, 1><<<dim3((NN + 127) / 128, HP / 128), 256, 0, stream>>>(
        aggb, W1t + (size_t)l * HP * DP, b1 + l * 600, 600, hid, HP, HP, NN, HP, nullptr);
    hipMemsetAsync(sums, 0, 2 * DP * 4, stream);
    k_gemm<HP, false, 0><<<dim3((NN + 127) / 128, 3), 256, 0, stream>>>(
        hid, W2t + (size_t)l * DP * HP, b2 + l * D, D, h2, D, D, NN, DP, sums);
    if (l < 4) k_bnapply<false><<<NN, DP, 0, stream>>>(h2, sums, gam + l * D, bet + l * D, hb, nullptr);
    else       k_bnapply<true ><<<NN, DP, 0, stream>>>(h2, sums, gam + l * D, bet + l * D, nullptr, out);
  }
}